// Round 1
// baseline (551.863 us; speedup 1.0000x reference)
//
#include <hip/hip_runtime.h>
#include <hip/hip_bf16.h>

// Problem constants
#define BB   8192      // batch
#define DD   2048      // embed dim
#define KK   512       // num directions
#define TT   17        // quadrature points

// ---------------- column stats (sum, sumsq) over rows, row-split + atomics ----
__global__ __launch_bounds__(256) void colstats_kernel(
    const float* __restrict__ X, float* __restrict__ sum, float* __restrict__ sumsq,
    int ncols, int rows_per_block) {
  int c = blockIdx.x * 256 + threadIdx.x;
  if (c >= ncols) return;
  int r0 = blockIdx.y * rows_per_block;
  float s = 0.f, ss = 0.f;
  for (int r = r0; r < r0 + rows_per_block; ++r) {
    float v = X[(size_t)r * ncols + c];
    s += v; ss += v * v;
  }
  atomicAdd(&sum[c], s);
  atomicAdd(&sumsq[c], ss);
}

// ---------------- direction column sumsq (reduce over D rows) ----------------
__global__ __launch_bounds__(256) void dirnorm_kernel(
    const float* __restrict__ dir, float* __restrict__ dirsumsq, int rows_per_block) {
  int k = blockIdx.x * 256 + threadIdx.x;
  int r0 = blockIdx.y * rows_per_block;
  float ss = 0.f;
  for (int r = r0; r < r0 + rows_per_block; ++r) {
    float v = dir[(size_t)r * KK + k];
    ss += v * v;
  }
  atomicAdd(&dirsumsq[k], ss);
}

// ---------------- finalize 1: invnorm per direction + var_floor --------------
__global__ __launch_bounds__(256) void finalize1_kernel(
    const float* __restrict__ colsum, const float* __restrict__ colsumsq,
    const float* __restrict__ dirsumsq, float* __restrict__ invnorm,
    float* __restrict__ varfloor) {
  int tid = threadIdx.x;
  for (int k = tid; k < KK; k += 256) {
    float n = sqrtf(dirsumsq[k]);
    invnorm[k] = 1.0f / fmaxf(n, 1e-12f);
  }
  float acc = 0.f;
  for (int d = tid; d < DD; d += 256) {
    float s = colsum[d], ss = colsumsq[d];
    float var = (ss - s * s / (float)BB) / (float)(BB - 1);
    float sd = sqrtf(fmaxf(var, 0.f));
    acc += fmaxf(1.0f - sd, 0.0f);
  }
  __shared__ float red[256];
  red[tid] = acc; __syncthreads();
  for (int s = 128; s > 0; s >>= 1) {
    if (tid < s) red[tid] += red[tid + s];
    __syncthreads();
  }
  if (tid == 0) *varfloor = red[0] / (float)DD;
}

// ---------------- fp32 tiled GEMM: proj = (z @ dir) * invnorm ----------------
// M=BB rows, N=KK cols, K=DD. Tile 64x64, BK=16, 256 threads, 4x4 per thread.
__global__ __launch_bounds__(256) void gemm_kernel(
    const float* __restrict__ A, const float* __restrict__ Bm,
    const float* __restrict__ invnorm, float* __restrict__ proj) {
  __shared__ float As[16][65];   // [k][m], +1 pad breaks store conflicts
  __shared__ float Bs[16][64];   // [k][n]
  int tid = threadIdx.x;
  int tx = tid & 15, ty = tid >> 4;
  int bn = blockIdx.x * 64;
  int bm = blockIdx.y * 64;
  float acc[4][4] = {};
  for (int k0 = 0; k0 < DD; k0 += 16) {
    #pragma unroll
    for (int i = 0; i < 4; ++i) {
      int e = tid + i * 256;
      int r = e >> 4, c = e & 15;          // 64 rows x 16 k
      As[c][r] = A[(size_t)(bm + r) * DD + k0 + c];
    }
    #pragma unroll
    for (int i = 0; i < 4; ++i) {
      int e = tid + i * 256;
      int r = e >> 6, c = e & 63;          // 16 k x 64 cols
      Bs[r][c] = Bm[(size_t)(k0 + r) * KK + bn + c];
    }
    __syncthreads();
    #pragma unroll
    for (int kk = 0; kk < 16; ++kk) {
      float ra[4], rb[4];
      #pragma unroll
      for (int i = 0; i < 4; ++i) ra[i] = As[kk][ty * 4 + i];
      #pragma unroll
      for (int j = 0; j < 4; ++j) rb[j] = Bs[kk][tx * 4 + j];
      #pragma unroll
      for (int i = 0; i < 4; ++i)
        #pragma unroll
        for (int j = 0; j < 4; ++j)
          acc[i][j] += ra[i] * rb[j];
    }
    __syncthreads();
  }
  #pragma unroll
  for (int j = 0; j < 4; ++j) {
    float inv = invnorm[bn + tx * 4 + j];
    #pragma unroll
    for (int i = 0; i < 4; ++i)
      proj[(size_t)(bm + ty * 4 + i) * KK + bn + tx * 4 + j] = acc[i][j] * inv;
  }
}

// ---------------- finalize 2: per-column mean + 1/(std+1e-8) ------------------
__global__ __launch_bounds__(256) void finalize2_kernel(
    const float* __restrict__ psum, const float* __restrict__ psumsq,
    float* __restrict__ mu, float* __restrict__ invsig) {
  int k = blockIdx.x * 256 + threadIdx.x;
  if (k >= KK) return;
  float s = psum[k], ss = psumsq[k];
  float m = s / (float)BB;
  float var = (ss - s * s / (float)BB) / (float)(BB - 1);
  float sd = sqrtf(fmaxf(var, 0.f));
  mu[k] = m;
  invsig[k] = 1.0f / (sd + 1e-8f);
}

// ---------------- ECF accumulation: sums of cos/sin(t_j * p) over B -----------
__global__ __launch_bounds__(256) void ecf_kernel(
    const float* __restrict__ proj, const float* __restrict__ mu,
    const float* __restrict__ invsig, float* __restrict__ ecfc,
    float* __restrict__ ecfs, int rows_per_block) {
  int k = blockIdx.x * 256 + threadIdx.x;
  float m = mu[k], is = invsig[k];
  int r0 = blockIdx.y * rows_per_block;
  const float dt = 2.0f / 17.0f;
  float ac[TT], asum[TT];
  #pragma unroll
  for (int j = 0; j < TT; ++j) { ac[j] = 0.f; asum[j] = 0.f; }
  for (int b = r0; b < r0 + rows_per_block; ++b) {
    float p = (proj[(size_t)b * KK + k] - m) * is;
    float th = dt * p;
    float s1, c1;
    __sincosf(th, &s1, &c1);
    float cj = c1, sj = s1;
    ac[0] += c1; asum[0] += s1;
    #pragma unroll
    for (int j = 1; j < TT; ++j) {
      float cn = cj * c1 - sj * s1;   // angle addition: cos((j+1)*th)
      float sn = sj * c1 + cj * s1;
      cj = cn; sj = sn;
      ac[j] += cj; asum[j] += sj;
    }
  }
  #pragma unroll
  for (int j = 0; j < TT; ++j) {
    atomicAdd(&ecfc[j * KK + k], ac[j]);
    atomicAdd(&ecfs[j * KK + k], asum[j]);
  }
}

// ---------------- final: integrand + quadrature + var_floor -------------------
__global__ __launch_bounds__(256) void final_kernel(
    const float* __restrict__ ecfc, const float* __restrict__ ecfs,
    const float* __restrict__ varfloor, float* __restrict__ out) {
  int tid = threadIdx.x;
  const float dt = 2.0f / 17.0f;
  const float invB = 1.0f / (float)BB;
  float acc = 0.f;
  for (int e = tid; e < TT * KK; e += 256) {
    int j = e >> 9;          // KK == 512
    float t = dt * (float)(j + 1);
    float w = (j == 0 || j == TT - 1) ? dt * 0.5f : dt;
    float r  = ecfc[e] * invB;
    float im = ecfs[e] * invB;
    float tcf = expf(-0.5f * t * t);
    float integ = r * r + im * im - 2.0f * r * tcf + tcf * tcf;
    acc += w * integ;
  }
  __shared__ float red[256];
  red[tid] = acc; __syncthreads();
  for (int s = 128; s > 0; s >>= 1) {
    if (tid < s) red[tid] += red[tid + s];
    __syncthreads();
  }
  if (tid == 0) out[0] = red[0] / (float)KK + varfloor[0];
}

extern "C" void kernel_launch(void* const* d_in, const int* in_sizes, int n_in,
                              void* d_out, int out_size, void* d_ws, size_t ws_size,
                              hipStream_t stream) {
  const float* z   = (const float*)d_in[0];   // (B, D)
  const float* dir = (const float*)d_in[1];   // (D, K)
  float* out = (float*)d_out;

  // workspace layout (floats)
  float* ws_f     = (float*)d_ws;
  float* proj     = ws_f;                       // B*K = 4,194,304
  float* acc_base = ws_f + (size_t)BB * KK;
  float* colsum   = acc_base;                   // DD
  float* colsumsq = colsum + DD;                // DD
  float* dirsumsq = colsumsq + DD;              // KK
  float* psum     = dirsumsq + KK;              // KK
  float* psumsq   = psum + KK;                  // KK
  float* ecfc     = psumsq + KK;                // TT*KK
  float* ecfs     = ecfc + TT * KK;             // TT*KK
  float* varfloor = ecfs + TT * KK;             // 1
  float* invnorm  = varfloor + 1;               // KK (no zeroing needed)
  float* mu       = invnorm + KK;               // KK
  float* invsig   = mu + KK;                    // KK

  size_t zero_floats = (size_t)(2 * DD + 3 * KK + 2 * TT * KK + 1);
  hipMemsetAsync(acc_base, 0, zero_floats * sizeof(float), stream);

  // 1. embedding column stats (2048 cols, 32 row-splits of 256 rows)
  colstats_kernel<<<dim3(DD / 256, 32), 256, 0, stream>>>(z, colsum, colsumsq, DD, BB / 32);
  // 2. direction column sumsq (512 cols, 16 row-splits of 128 rows)
  dirnorm_kernel<<<dim3(KK / 256, 16), 256, 0, stream>>>(dir, dirsumsq, DD / 16);
  // 3. invnorm + var_floor
  finalize1_kernel<<<1, 256, 0, stream>>>(colsum, colsumsq, dirsumsq, invnorm, varfloor);
  // 4. GEMM: proj = (z @ dir) * invnorm   (grid: N/64 x M/64)
  gemm_kernel<<<dim3(KK / 64, BB / 64), 256, 0, stream>>>(z, dir, invnorm, proj);
  // 5. proj column stats
  colstats_kernel<<<dim3(KK / 256, 32), 256, 0, stream>>>(proj, psum, psumsq, KK, BB / 32);
  // 6. mu, invsig
  finalize2_kernel<<<dim3((KK + 255) / 256), 256, 0, stream>>>(psum, psumsq, mu, invsig);
  // 7. ECF sums
  ecf_kernel<<<dim3(KK / 256, 32), 256, 0, stream>>>(proj, mu, invsig, ecfc, ecfs, BB / 32);
  // 8. final scalar
  final_kernel<<<1, 256, 0, stream>>>(ecfc, ecfs, varfloor, out);
}

// Round 2
// 219.749 us; speedup vs baseline: 2.5113x; 2.5113x over previous
//
#include <hip/hip_runtime.h>
#include <hip/hip_bf16.h>

// Problem constants
#define BB   8192      // batch
#define DD   2048      // embed dim
#define KK   512       // num directions
#define TT   17        // quadrature points

// GEMM tile
#define BM   64
#define BN   128
#define BK   32
#define NT   (DD / BK)   // 64 K-steps

typedef __attribute__((ext_vector_type(8))) short  bf16x8;
typedef __attribute__((ext_vector_type(4))) float  f32x4;

// async global->LDS, 16B per lane, wave-uniform LDS base + lane*16
__device__ __forceinline__ void gload16(const void* g, void* l) {
  __builtin_amdgcn_global_load_lds(
      (const __attribute__((address_space(1))) void*)g,
      (__attribute__((address_space(3))) void*)l,
      16, 0, 0);
}

// ---------- prep z: colstats (fp32, for var_floor) + bf16 conversion ----------
// thread: 4 consecutive cols x rows_per_block rows. float4 in, ushort4 out.
__global__ __launch_bounds__(256) void prep_z_kernel(
    const float* __restrict__ z, unsigned short* __restrict__ zb,
    float* __restrict__ colsum, float* __restrict__ colsumsq, int rows_per_block) {
  int c4 = blockIdx.x * 256 + threadIdx.x;      // 0..511
  int c = c4 * 4;
  int r0 = blockIdx.y * rows_per_block;
  float s[4] = {0.f, 0.f, 0.f, 0.f}, ss[4] = {0.f, 0.f, 0.f, 0.f};
  for (int r = r0; r < r0 + rows_per_block; ++r) {
    float4 v = *(const float4*)&z[(size_t)r * DD + c];
    float f[4] = {v.x, v.y, v.z, v.w};
    ushort4 o;
    unsigned short* op = (unsigned short*)&o;
    #pragma unroll
    for (int i = 0; i < 4; ++i) {
      s[i] += f[i]; ss[i] += f[i] * f[i];
      __hip_bfloat16 h = __float2bfloat16(f[i]);
      op[i] = *(unsigned short*)&h;
    }
    *(ushort4*)&zb[(size_t)r * DD + c] = o;
  }
  #pragma unroll
  for (int i = 0; i < 4; ++i) {
    atomicAdd(&colsum[c + i], s[i]);
    atomicAdd(&colsumsq[c + i], ss[i]);
  }
}

// ---------- direction column sumsq (fp32, exact match to reference norm) ------
__global__ __launch_bounds__(256) void dirnorm_kernel(
    const float* __restrict__ dir, float* __restrict__ dirsumsq, int rows_per_block) {
  int k = blockIdx.x * 256 + threadIdx.x;
  int r0 = blockIdx.y * rows_per_block;
  float ss = 0.f;
  for (int r = r0; r < r0 + rows_per_block; ++r) {
    float v = dir[(size_t)r * KK + k];
    ss += v * v;
  }
  atomicAdd(&dirsumsq[k], ss);
}

// ---------- finalize 1: invnorm per direction + var_floor ---------------------
__global__ __launch_bounds__(256) void finalize1_kernel(
    const float* __restrict__ colsum, const float* __restrict__ colsumsq,
    const float* __restrict__ dirsumsq, float* __restrict__ invnorm,
    float* __restrict__ varfloor) {
  int tid = threadIdx.x;
  for (int k = tid; k < KK; k += 256) {
    float n = sqrtf(dirsumsq[k]);
    invnorm[k] = 1.0f / fmaxf(n, 1e-12f);
  }
  float acc = 0.f;
  for (int d = tid; d < DD; d += 256) {
    float s = colsum[d], ss = colsumsq[d];
    float var = (ss - s * s / (float)BB) / (float)(BB - 1);
    float sd = sqrtf(fmaxf(var, 0.f));
    acc += fmaxf(1.0f - sd, 0.0f);
  }
  __shared__ float red[256];
  red[tid] = acc; __syncthreads();
  for (int s = 128; s > 0; s >>= 1) {
    if (tid < s) red[tid] += red[tid + s];
    __syncthreads();
  }
  if (tid == 0) *varfloor = red[0] / (float)DD;
}

// ---------- dirT: normalize + bf16 + transpose (D,K)->(K,D) -------------------
__global__ __launch_bounds__(256) void dirT_kernel(
    const float* __restrict__ dir, const float* __restrict__ invnorm,
    unsigned short* __restrict__ dT) {
  __shared__ unsigned short tile[64][65];   // +1 pad
  int n0 = blockIdx.x * 64;   // K dim (8 blocks)
  int d0 = blockIdx.y * 64;   // D dim (32 blocks)
  int tx = threadIdx.x & 63, ty = threadIdx.x >> 6;
  float inv = invnorm[n0 + tx];
  #pragma unroll
  for (int i = 0; i < 16; ++i) {
    int dr = ty + i * 4;
    float v = dir[(size_t)(d0 + dr) * KK + n0 + tx] * inv;
    __hip_bfloat16 h = __float2bfloat16(v);
    tile[dr][tx] = *(unsigned short*)&h;
  }
  __syncthreads();
  #pragma unroll
  for (int i = 0; i < 16; ++i) {
    int nr = ty + i * 4;
    dT[(size_t)(n0 + nr) * DD + d0 + tx] = tile[tx][nr];
  }
}

// ---------- bf16 MFMA GEMM: proj(B,K) = zb(B,D) @ dT(K,D)^T -------------------
// 512 blocks (2/CU), 256 threads = 4 waves (2m x 2n), wave tile 32x64.
// 2-phase double-buffered LDS, global_load_lds width 16, raw barrier + vmcnt.
__global__ __launch_bounds__(256) void gemm_bf16_kernel(
    const unsigned short* __restrict__ zb, const unsigned short* __restrict__ dT,
    float* __restrict__ proj) {
  __shared__ __align__(16) short As[2][BM * BK];   // [m][k], 4KB/buf
  __shared__ __align__(16) short Bs[2][BN * BK];   // [n][k], 8KB/buf

  int tid = threadIdx.x;
  int w = tid >> 6, l = tid & 63;

  // XCD-chunked swizzle: the 4 n-blocks of one m-block land on ONE XCD
  // (round-robin is bid%8), so the z row-panel is fetched once per XCD L2.
  int bid = blockIdx.x;               // 0..511
  int xcd = bid & 7, slot = bid >> 3; // slot 0..63
  int bmi = ((slot >> 2) << 3) | xcd; // m-block 0..127
  int bni = slot & 3;                 // n-block 0..3
  int bm = bmi * BM, bn = bni * BN;

  // staging: lane l loads 16B at row (l>>2), kcol (l&3)*8
  const unsigned short* gA = zb + (size_t)(bm + w * 16 + (l >> 2)) * DD + (l & 3) * 8;
  const unsigned short* gB = dT + (size_t)(bn + w * 32 + (l >> 2)) * DD + (l & 3) * 8;

#define STAGE(buf, kt) do {                                        \
    const unsigned short* ga_ = gA + (kt) * BK;                    \
    const unsigned short* gb_ = gB + (kt) * BK;                    \
    gload16(ga_,           &As[buf][(w * 16) * BK]);               \
    gload16(gb_,           &Bs[buf][(w * 32) * BK]);               \
    gload16(gb_ + 16 * DD, &Bs[buf][(w * 32 + 16) * BK]);          \
  } while (0)

  int wm = (w >> 1) * 32, wn = (w & 1) * 64;
  int fr = l & 15, fq = l >> 4;
  int offA = (wm + fr) * BK + fq * 8;
  int offB = (wn + fr) * BK + fq * 8;

  f32x4 acc[2][4];
  f32x4 zero4 = {0.f, 0.f, 0.f, 0.f};
  #pragma unroll
  for (int mi = 0; mi < 2; ++mi)
    #pragma unroll
    for (int ni = 0; ni < 4; ++ni) acc[mi][ni] = zero4;

  STAGE(0, 0);
  asm volatile("s_waitcnt vmcnt(0)" ::: "memory");
  __builtin_amdgcn_s_barrier();

  for (int t = 0; t < NT; ++t) {
    int cur = t & 1;
    if (t + 1 < NT) STAGE(cur ^ 1, t + 1);    // issue next-tile loads first
    bf16x8 av[2], bv[4];
    #pragma unroll
    for (int mi = 0; mi < 2; ++mi) av[mi] = *(const bf16x8*)&As[cur][offA + mi * 16 * BK];
    #pragma unroll
    for (int ni = 0; ni < 4; ++ni) bv[ni] = *(const bf16x8*)&Bs[cur][offB + ni * 16 * BK];
    #pragma unroll
    for (int mi = 0; mi < 2; ++mi)
      #pragma unroll
      for (int ni = 0; ni < 4; ++ni)
        acc[mi][ni] = __builtin_amdgcn_mfma_f32_16x16x32_bf16(av[mi], bv[ni], acc[mi][ni], 0, 0, 0);
    asm volatile("s_waitcnt vmcnt(0)" ::: "memory");   // next tile staged
    __builtin_amdgcn_s_barrier();
  }
#undef STAGE

  // C/D layout: col = lane&15, row = (lane>>4)*4 + j  [m89-verified]
  #pragma unroll
  for (int mi = 0; mi < 2; ++mi)
    #pragma unroll
    for (int ni = 0; ni < 4; ++ni)
      #pragma unroll
      for (int j = 0; j < 4; ++j)
        proj[(size_t)(bm + wm + mi * 16 + fq * 4 + j) * KK + (bn + wn + ni * 16 + fr)] =
            acc[mi][ni][j];
}

// ---------- column stats (sum, sumsq) over rows ---------------------------------
__global__ __launch_bounds__(256) void colstats_kernel(
    const float* __restrict__ X, float* __restrict__ sum, float* __restrict__ sumsq,
    int ncols, int rows_per_block) {
  int c = blockIdx.x * 256 + threadIdx.x;
  if (c >= ncols) return;
  int r0 = blockIdx.y * rows_per_block;
  float s = 0.f, ss = 0.f;
  for (int r = r0; r < r0 + rows_per_block; ++r) {
    float v = X[(size_t)r * ncols + c];
    s += v; ss += v * v;
  }
  atomicAdd(&sum[c], s);
  atomicAdd(&sumsq[c], ss);
}

// ---------- finalize 2: per-column mean + 1/(std+1e-8) --------------------------
__global__ __launch_bounds__(256) void finalize2_kernel(
    const float* __restrict__ psum, const float* __restrict__ psumsq,
    float* __restrict__ mu, float* __restrict__ invsig) {
  int k = blockIdx.x * 256 + threadIdx.x;
  if (k >= KK) return;
  float s = psum[k], ss = psumsq[k];
  float m = s / (float)BB;
  float var = (ss - s * s / (float)BB) / (float)(BB - 1);
  float sd = sqrtf(fmaxf(var, 0.f));
  mu[k] = m;
  invsig[k] = 1.0f / (sd + 1e-8f);
}

// ---------- ECF accumulation: sums of cos/sin(t_j * p) over B -------------------
__global__ __launch_bounds__(256) void ecf_kernel(
    const float* __restrict__ proj, const float* __restrict__ mu,
    const float* __restrict__ invsig, float* __restrict__ ecfc,
    float* __restrict__ ecfs, int rows_per_block) {
  int k = blockIdx.x * 256 + threadIdx.x;
  float m = mu[k], is = invsig[k];
  int r0 = blockIdx.y * rows_per_block;
  const float dt = 2.0f / 17.0f;
  float ac[TT], asum[TT];
  #pragma unroll
  for (int j = 0; j < TT; ++j) { ac[j] = 0.f; asum[j] = 0.f; }
  for (int b = r0; b < r0 + rows_per_block; ++b) {
    float p = (proj[(size_t)b * KK + k] - m) * is;
    float th = dt * p;
    float s1, c1;
    __sincosf(th, &s1, &c1);
    float cj = c1, sj = s1;
    ac[0] += c1; asum[0] += s1;
    #pragma unroll
    for (int j = 1; j < TT; ++j) {
      float cn = cj * c1 - sj * s1;   // angle addition
      float sn = sj * c1 + cj * s1;
      cj = cn; sj = sn;
      ac[j] += cj; asum[j] += sj;
    }
  }
  #pragma unroll
  for (int j = 0; j < TT; ++j) {
    atomicAdd(&ecfc[j * KK + k], ac[j]);
    atomicAdd(&ecfs[j * KK + k], asum[j]);
  }
}

// ---------- final: integrand + quadrature + var_floor ---------------------------
__global__ __launch_bounds__(256) void final_kernel(
    const float* __restrict__ ecfc, const float* __restrict__ ecfs,
    const float* __restrict__ varfloor, float* __restrict__ out) {
  int tid = threadIdx.x;
  const float dt = 2.0f / 17.0f;
  const float invB = 1.0f / (float)BB;
  float acc = 0.f;
  for (int e = tid; e < TT * KK; e += 256) {
    int j = e >> 9;          // KK == 512
    float t = dt * (float)(j + 1);
    float w = (j == 0 || j == TT - 1) ? dt * 0.5f : dt;
    float r  = ecfc[e] * invB;
    float im = ecfs[e] * invB;
    float tcf = expf(-0.5f * t * t);
    float integ = r * r + im * im - 2.0f * r * tcf + tcf * tcf;
    acc += w * integ;
  }
  __shared__ float red[256];
  red[tid] = acc; __syncthreads();
  for (int s = 128; s > 0; s >>= 1) {
    if (tid < s) red[tid] += red[tid + s];
    __syncthreads();
  }
  if (tid == 0) out[0] = red[0] / (float)KK + varfloor[0];
}

extern "C" void kernel_launch(void* const* d_in, const int* in_sizes, int n_in,
                              void* d_out, int out_size, void* d_ws, size_t ws_size,
                              hipStream_t stream) {
  const float* z   = (const float*)d_in[0];   // (B, D) fp32
  const float* dir = (const float*)d_in[1];   // (D, K) fp32
  float* out = (float*)d_out;

  // workspace layout (bytes)
  uint8_t* w8 = (uint8_t*)d_ws;
  unsigned short* zb = (unsigned short*)w8;                       // 32 MB bf16
  unsigned short* dT = (unsigned short*)(w8 + 33554432);          //  2 MB bf16
  float* proj        = (float*)(w8 + 35651584);                   // 16 MB fp32
  float* stat        = (float*)(w8 + 52428800);
  float* colsum   = stat;                  // DD
  float* colsumsq = colsum + DD;           // DD
  float* dirsumsq = colsumsq + DD;         // KK
  float* psum     = dirsumsq + KK;         // KK
  float* psumsq   = psum + KK;             // KK
  float* ecfc     = psumsq + KK;           // TT*KK
  float* ecfs     = ecfc + TT * KK;        // TT*KK
  float* varfloor = ecfs + TT * KK;        // 1
  float* invnorm  = varfloor + 1;          // KK
  float* mu       = invnorm + KK;          // KK
  float* invsig   = mu + KK;               // KK

  size_t zero_floats = (size_t)(2 * DD + 3 * KK + 2 * TT * KK + 1);
  hipMemsetAsync(stat, 0, zero_floats * sizeof(float), stream);

  // 1. z -> bf16 + colstats (var_floor inputs stay exact fp32)
  prep_z_kernel<<<dim3(2, 128), 256, 0, stream>>>(z, zb, colsum, colsumsq, BB / 128);
  // 2. direction column sumsq (fp32, exact)
  dirnorm_kernel<<<dim3(2, 16), 256, 0, stream>>>(dir, dirsumsq, DD / 16);
  // 3. invnorm + var_floor
  finalize1_kernel<<<1, 256, 0, stream>>>(colsum, colsumsq, dirsumsq, invnorm, varfloor);
  // 4. dir -> normalized bf16 transpose (K, D)
  dirT_kernel<<<dim3(8, 32), 256, 0, stream>>>(dir, invnorm, dT);
  // 5. bf16 MFMA GEMM
  gemm_bf16_kernel<<<dim3(512), 256, 0, stream>>>(zb, dT, proj);
  // 6. proj column stats
  colstats_kernel<<<dim3(2, 64), 256, 0, stream>>>(proj, psum, psumsq, KK, BB / 64);
  // 7. mu, invsig
  finalize2_kernel<<<dim3(2), 256, 0, stream>>>(psum, psumsq, mu, invsig);
  // 8. ECF sums
  ecf_kernel<<<dim3(2, 64), 256, 0, stream>>>(proj, mu, invsig, ecfc, ecfs, BB / 64);
  // 9. final scalar
  final_kernel<<<1, 256, 0, stream>>>(ecfc, ecfs, varfloor, out);
}

// Round 4
// 130.820 us; speedup vs baseline: 4.2185x; 1.6798x over previous
//
#include <hip/hip_runtime.h>
#include <hip/hip_bf16.h>

// Problem constants
#define BB   8192      // batch
#define DD   2048      // embed dim
#define KK   512       // num directions
#define TT   17        // quadrature points

// GEMM tile: m97 geometry, R1-proven 2-phase sync (1 barrier + vmcnt(0)/iter)
#define BM   128
#define BN   128
#define BK   64
#define NT   (DD / BK)   // 32 K-steps

typedef __attribute__((ext_vector_type(8))) short  bf16x8;
typedef __attribute__((ext_vector_type(4))) float  f32x4;

__device__ __forceinline__ void gload16(const void* g, void* l) {
  __builtin_amdgcn_global_load_lds(
      (const __attribute__((address_space(1))) void*)g,
      (__attribute__((address_space(3))) void*)l,
      16, 0, 0);
}

// ---------- prep z: colstats (fp32, for var_floor) + bf16 conversion ----------
__global__ __launch_bounds__(256) void prep_z_kernel(
    const float* __restrict__ z, unsigned short* __restrict__ zb,
    float* __restrict__ colsum, float* __restrict__ colsumsq, int rows_per_block) {
  int c4 = blockIdx.x * 256 + threadIdx.x;      // 0..511
  int c = c4 * 4;
  int r0 = blockIdx.y * rows_per_block;
  float s[4] = {0.f, 0.f, 0.f, 0.f}, ss[4] = {0.f, 0.f, 0.f, 0.f};
  for (int r = r0; r < r0 + rows_per_block; ++r) {
    float4 v = *(const float4*)&z[(size_t)r * DD + c];
    float f[4] = {v.x, v.y, v.z, v.w};
    ushort4 o;
    unsigned short* op = (unsigned short*)&o;
    #pragma unroll
    for (int i = 0; i < 4; ++i) {
      s[i] += f[i]; ss[i] += f[i] * f[i];
      __hip_bfloat16 h = __float2bfloat16(f[i]);
      op[i] = *(unsigned short*)&h;
    }
    *(ushort4*)&zb[(size_t)r * DD + c] = o;
  }
  #pragma unroll
  for (int i = 0; i < 4; ++i) {
    atomicAdd(&colsum[c + i], s[i]);
    atomicAdd(&colsumsq[c + i], ss[i]);
  }
}

// ---------- direction column sumsq (fp32, exact) ------------------------------
__global__ __launch_bounds__(256) void dirnorm_kernel(
    const float* __restrict__ dir, float* __restrict__ dirsumsq, int rows_per_block) {
  int k = blockIdx.x * 256 + threadIdx.x;
  int r0 = blockIdx.y * rows_per_block;
  float ss = 0.f;
  for (int r = r0; r < r0 + rows_per_block; ++r) {
    float v = dir[(size_t)r * KK + k];
    ss += v * v;
  }
  atomicAdd(&dirsumsq[k], ss);
}

// ---------- finalize 1: invnorm + var_floor (seeds out[0]) --------------------
__global__ __launch_bounds__(256) void finalize1_kernel(
    const float* __restrict__ colsum, const float* __restrict__ colsumsq,
    const float* __restrict__ dirsumsq, float* __restrict__ invnorm,
    float* __restrict__ out) {
  int tid = threadIdx.x;
  for (int k = tid; k < KK; k += 256) {
    float n = sqrtf(dirsumsq[k]);
    invnorm[k] = 1.0f / fmaxf(n, 1e-12f);
  }
  float acc = 0.f;
  for (int d = tid; d < DD; d += 256) {
    float s = colsum[d], ss = colsumsq[d];
    float var = (ss - s * s / (float)BB) / (float)(BB - 1);
    float sd = sqrtf(fmaxf(var, 0.f));
    acc += fmaxf(1.0f - sd, 0.0f);
  }
  __shared__ float red[256];
  red[tid] = acc; __syncthreads();
  for (int s = 128; s > 0; s >>= 1) {
    if (tid < s) red[tid] += red[tid + s];
    __syncthreads();
  }
  if (tid == 0) out[0] = red[0] / (float)DD;   // ecf_final atomically adds the rest
}

// ---------- dirT: normalize + bf16 + transpose (D,K)->(K,D) -------------------
__global__ __launch_bounds__(256) void dirT_kernel(
    const float* __restrict__ dir, const float* __restrict__ invnorm,
    unsigned short* __restrict__ dT) {
  __shared__ unsigned short tile[64][65];   // +1 pad
  int n0 = blockIdx.x * 64;   // K dim (8 blocks)
  int d0 = blockIdx.y * 64;   // D dim (32 blocks)
  int tx = threadIdx.x & 63, ty = threadIdx.x >> 6;
  float inv = invnorm[n0 + tx];
  #pragma unroll
  for (int i = 0; i < 16; ++i) {
    int dr = ty + i * 4;
    float v = dir[(size_t)(d0 + dr) * KK + n0 + tx] * inv;
    __hip_bfloat16 h = __float2bfloat16(v);
    tile[dr][tx] = *(unsigned short*)&h;
  }
  __syncthreads();
  #pragma unroll
  for (int i = 0; i < 16; ++i) {
    int nr = ty + i * 4;
    dT[(size_t)(n0 + nr) * DD + d0 + tx] = tile[tx][nr];
  }
}

// ---------- bf16 MFMA GEMM: proj(B,K) = zb(B,D) @ dT(K,D)^T -------------------
// 256 blocks (1/CU), 4 waves (2m x 2n), wave tile 64x64 (4x4 acc).
// R1-PROVEN sync: STAGE(next buf) at loop top; reads+MFMA; vmcnt(0)+barrier.
// T2 XOR-swizzle via pre-swizzled global source (LDS dest stays linear).
__global__ __launch_bounds__(256) void gemm_bf16_kernel(
    const unsigned short* __restrict__ zb, const unsigned short* __restrict__ dT,
    float* __restrict__ proj, float* __restrict__ psum, float* __restrict__ psumsq) {
  __shared__ __align__(16) short As[2][BM * BK];   // 16KB/buf
  __shared__ __align__(16) short Bs[2][BN * BK];   // 16KB/buf

  int tid = threadIdx.x;
  int w = tid >> 6, l = tid & 63;

  // XCD-chunked swizzle (bijective): XCD x owns m-blocks [x*8, x*8+8)
  int bid = blockIdx.x;               // 0..255
  int xcd = bid & 7, slot = bid >> 3; // slot 0..31
  int bmi = xcd * 8 + (slot >> 2);    // 0..63
  int bni = slot & 3;                 // 0..3
  int bm = bmi * BM, bn = bni * BN;

  // Staging: wave w stages rows [w*32, w*32+32) of A and B per K-tile, in
  // 4 strips of 8 rows. LDS dest linear (base + lane*16B); the 16B-granule
  // permutation g_lds = g_global ^ (row&7) is applied by pre-swizzling the
  // global column (rule #21: inverse-swz source + swz read, same involution).
  int lr = l >> 3;                     // row within 8-row strip (0..7)
  int gran = (l & 7) ^ lr;             // global granule this lane fetches
  const unsigned short* aSrc = zb + (size_t)(bm + w * 32 + lr) * DD + gran * 8;
  const unsigned short* bSrc = dT + (size_t)(bn + w * 32 + lr) * DD + gran * 8;

#define STAGE(buf, kt) do {                                                 \
    const unsigned short* a_ = aSrc + (kt) * BK;                            \
    const unsigned short* b_ = bSrc + (kt) * BK;                            \
    gload16(a_ + 0 * 8 * DD, &As[buf][(w * 32 + 0) * BK]);                  \
    gload16(b_ + 0 * 8 * DD, &Bs[buf][(w * 32 + 0) * BK]);                  \
    gload16(a_ + 1 * 8 * DD, &As[buf][(w * 32 + 8) * BK]);                  \
    gload16(b_ + 1 * 8 * DD, &Bs[buf][(w * 32 + 8) * BK]);                  \
    gload16(a_ + 2 * 8 * DD, &As[buf][(w * 32 + 16) * BK]);                 \
    gload16(b_ + 2 * 8 * DD, &Bs[buf][(w * 32 + 16) * BK]);                 \
    gload16(a_ + 3 * 8 * DD, &As[buf][(w * 32 + 24) * BK]);                 \
    gload16(b_ + 3 * 8 * DD, &Bs[buf][(w * 32 + 24) * BK]);                 \
  } while (0)

  int wm = (w >> 1) * 64, wn = (w & 1) * 64;
  int fr = l & 15, fq = l >> 4;
  int fx = fr & 7;                     // = (LDS row)&7 for all fragment rows

  f32x4 acc[4][4];
  f32x4 zero4 = {0.f, 0.f, 0.f, 0.f};
  #pragma unroll
  for (int mi = 0; mi < 4; ++mi)
    #pragma unroll
    for (int ni = 0; ni < 4; ++ni) acc[mi][ni] = zero4;

  STAGE(0, 0);
  asm volatile("s_waitcnt vmcnt(0)" ::: "memory");
  __builtin_amdgcn_s_barrier();

  for (int t = 0; t < NT; ++t) {
    int cur = t & 1;
    if (t + 1 < NT) STAGE(cur ^ 1, t + 1);   // issue next-tile loads first
    #pragma unroll
    for (int kk = 0; kk < 2; ++kk) {
      bf16x8 av[4], bv[4];
      int go = ((kk * 4 + fq) ^ fx) * 8;     // swizzled 16B-granule read
      #pragma unroll
      for (int mi = 0; mi < 4; ++mi)
        av[mi] = *(const bf16x8*)&As[cur][(wm + mi * 16 + fr) * BK + go];
      #pragma unroll
      for (int ni = 0; ni < 4; ++ni)
        bv[ni] = *(const bf16x8*)&Bs[cur][(wn + ni * 16 + fr) * BK + go];
      #pragma unroll
      for (int mi = 0; mi < 4; ++mi)
        #pragma unroll
        for (int ni = 0; ni < 4; ++ni)
          acc[mi][ni] = __builtin_amdgcn_mfma_f32_16x16x32_bf16(av[mi], bv[ni], acc[mi][ni], 0, 0, 0);
    }
    asm volatile("s_waitcnt vmcnt(0)" ::: "memory");   // next tile staged
    __builtin_amdgcn_s_barrier();                      // + all reads of cur done
  }
#undef STAGE

  // Epilogue: write proj + fused column stats (sum, sumsq over wave's 64 rows)
  #pragma unroll
  for (int ni = 0; ni < 4; ++ni) {
    float s = 0.f, q = 0.f;
    int col = bn + wn + ni * 16 + fr;
    #pragma unroll
    for (int mi = 0; mi < 4; ++mi)
      #pragma unroll
      for (int j = 0; j < 4; ++j) {
        float v = acc[mi][ni][j];
        s += v; q += v * v;
        proj[(size_t)(bm + wm + mi * 16 + fq * 4 + j) * KK + col] = v;
      }
    s += __shfl_xor(s, 16); q += __shfl_xor(q, 16);
    s += __shfl_xor(s, 32); q += __shfl_xor(q, 32);
    if (fq == 0) {
      atomicAdd(&psum[col], s);
      atomicAdd(&psumsq[col], q);
    }
  }
}

// ---------- finalize 2: per-column mean + 1/(std+1e-8) ------------------------
__global__ __launch_bounds__(256) void finalize2_kernel(
    const float* __restrict__ psum, const float* __restrict__ psumsq,
    float* __restrict__ mu, float* __restrict__ invsig) {
  int k = blockIdx.x * 256 + threadIdx.x;
  if (k >= KK) return;
  float s = psum[k], ss = psumsq[k];
  float m = s / (float)BB;
  float var = (ss - s * s / (float)BB) / (float)(BB - 1);
  float sd = sqrtf(fmaxf(var, 0.f));
  mu[k] = m;
  invsig[k] = 1.0f / (sd + 1e-8f);
}

// ---------- ECF: block (kx,ry) covers 64 k-cols x 128 rows --------------------
// 4 waves share the same 64 k (lane = k); wave w does rows [ry*128+w*32, +32).
// Chebyshev recurrence. Cross-wave LDS reduce -> per-block partial (no atomics).
__global__ __launch_bounds__(256) void ecf_kernel(
    const float* __restrict__ proj, const float* __restrict__ mu,
    const float* __restrict__ invsig, float* __restrict__ part) {
  int kx = blockIdx.x, ry = blockIdx.y;
  int tid = threadIdx.x;
  int kl = tid & 63, w = tid >> 6;
  int k = kx * 64 + kl;
  float m = mu[k], is = invsig[k];
  int r0 = ry * 128 + w * 32;
  const float dt = 2.0f / 17.0f;

  float ac[TT], as[TT];
  #pragma unroll
  for (int j = 0; j < TT; ++j) { ac[j] = 0.f; as[j] = 0.f; }

  #pragma unroll 4
  for (int i = 0; i < 32; ++i) {
    float p = (proj[(size_t)(r0 + i) * KK + k] - m) * is;
    float th = dt * p;
    float s1, c1;
    __sincosf(th, &s1, &c1);
    float tc = 2.0f * c1;
    float cj = c1, sj = s1, cjm = 1.0f, sjm = 0.0f;
    ac[0] += c1; as[0] += s1;
    #pragma unroll
    for (int j = 1; j < TT; ++j) {
      float cn = tc * cj - cjm;
      float sn = tc * sj - sjm;
      cjm = cj; sjm = sj; cj = cn; sj = sn;
      ac[j] += cj; as[j] += sj;
    }
  }

  __shared__ float red[4 * 2176];     // [wave][kl*34 + jj]
  int base = w * 2176 + kl * 34;
  #pragma unroll
  for (int j = 0; j < TT; ++j) {
    red[base + j] = ac[j];
    red[base + 17 + j] = as[j];
  }
  __syncthreads();
  for (int idx = tid; idx < 2176; idx += 256) {
    float v = red[idx] + red[2176 + idx] + red[4352 + idx] + red[6528 + idx];
    part[(size_t)(ry * 8 + kx) * 2176 + idx] = v;
  }
}

// ---------- reduce partials -> integrand -> atomic add into out ---------------
__global__ __launch_bounds__(256) void ecf_final_kernel(
    const float* __restrict__ part, float* __restrict__ out) {
  int gi = blockIdx.x * 256 + threadIdx.x;   // 0..8703 = 512k x 17j
  int kx = gi / 1088;                        // 1088 = 64*17
  int r2 = gi - kx * 1088;
  int kl = r2 / 17;
  int j  = r2 - kl * 17;
  const float dt = 2.0f / 17.0f;
  float cs = 0.f, ss = 0.f;
  for (int ry = 0; ry < 64; ++ry) {
    size_t b = (size_t)(ry * 8 + kx) * 2176 + kl * 34;
    cs += part[b + j];
    ss += part[b + 17 + j];
  }
  const float invB = 1.0f / (float)BB;
  float r  = cs * invB;
  float im = ss * invB;
  float t = dt * (float)(j + 1);
  float wq = (j == 0 || j == TT - 1) ? dt * 0.5f : dt;
  float tcf = expf(-0.5f * t * t);
  float val = wq * (r * r + im * im - 2.0f * r * tcf + tcf * tcf) / (float)KK;

  __shared__ float red[256];
  int tid = threadIdx.x;
  red[tid] = val; __syncthreads();
  for (int s = 128; s > 0; s >>= 1) {
    if (tid < s) red[tid] += red[tid + s];
    __syncthreads();
  }
  if (tid == 0) atomicAdd(out, red[0]);
}

extern "C" void kernel_launch(void* const* d_in, const int* in_sizes, int n_in,
                              void* d_out, int out_size, void* d_ws, size_t ws_size,
                              hipStream_t stream) {
  const float* z   = (const float*)d_in[0];   // (B, D) fp32
  const float* dir = (const float*)d_in[1];   // (D, K) fp32
  float* out = (float*)d_out;

  // workspace layout (bytes)
  uint8_t* w8 = (uint8_t*)d_ws;
  unsigned short* zb = (unsigned short*)w8;                   // 32 MB bf16
  float* part        = (float*)w8;                            // 4.46 MB (reuses zb AFTER gemm)
  unsigned short* dT = (unsigned short*)(w8 + 33554432);      //  2 MB bf16
  float* proj        = (float*)(w8 + 35651584);               // 16 MB fp32
  float* stat        = (float*)(w8 + 52428800);
  float* colsum   = stat;                  // DD
  float* colsumsq = colsum + DD;           // DD
  float* dirsumsq = colsumsq + DD;         // KK
  float* psum     = dirsumsq + KK;         // KK
  float* psumsq   = psum + KK;             // KK
  float* invnorm  = psumsq + KK;           // KK
  float* mu       = invnorm + KK;          // KK
  float* invsig   = mu + KK;               // KK

  size_t zero_floats = (size_t)(2 * DD + 3 * KK);
  hipMemsetAsync(stat, 0, zero_floats * sizeof(float), stream);

  // 1. z -> bf16 + colstats
  prep_z_kernel<<<dim3(2, 256), 256, 0, stream>>>(z, zb, colsum, colsumsq, BB / 256);
  // 2. direction column sumsq
  dirnorm_kernel<<<dim3(2, 64), 256, 0, stream>>>(dir, dirsumsq, DD / 64);
  // 3. invnorm + var_floor (seeds out[0])
  finalize1_kernel<<<1, 256, 0, stream>>>(colsum, colsumsq, dirsumsq, invnorm, out);
  // 4. dir -> normalized bf16 transpose (K, D)
  dirT_kernel<<<dim3(8, 32), 256, 0, stream>>>(dir, invnorm, dT);
  // 5. bf16 MFMA GEMM (+fused proj column stats)
  gemm_bf16_kernel<<<dim3(256), 256, 0, stream>>>(zb, dT, proj, psum, psumsq);
  // 6. mu, invsig
  finalize2_kernel<<<dim3(2), 256, 0, stream>>>(psum, psumsq, mu, invsig);
  // 7. ECF partial sums (part overwrites zb region -- zb already consumed)
  ecf_kernel<<<dim3(8, 64), 256, 0, stream>>>(proj, mu, invsig, part);
  // 8. reduce + integrand + quadrature -> out
  ecf_final_kernel<<<dim3(34), 256, 0, stream>>>(part, out);
}